// Round 5
// baseline (240.630 us; speedup 1.0000x reference)
//
#include <hip/hip_runtime.h>
#include <hip/hip_bf16.h>

#define NQ 6

typedef __attribute__((ext_vector_type(8))) short short8;
typedef __attribute__((ext_vector_type(4))) float floatx4;

// ---------------- ws layout (bytes) ----------------
// U_circ : float2[64*64]        @ 0        (32768 B)
// Mq     : float[18]            @ 32768
// cq     : float[3]             @ 32840
// W1bf   : short[64*2048]       @ 36864    (262144 B)
#define WS_MQ_F   8192        // float offset of Mq
#define WS_CQ_F   (8192+18)
#define WS_W1BF_B 36864

// ============ K0: prep — U_circ columns, Mq/cq, W1->bf16 ============
__global__ __launch_bounds__(64) void prep_kernel(
    const float* __restrict__ qw, int n_layers,
    const float* __restrict__ W1, const float* __restrict__ Wq,
    const float* __restrict__ bq, const float* __restrict__ Wf,
    const float* __restrict__ bf, float* __restrict__ ws_f,
    short* __restrict__ w1bf)
{
    const int blk  = blockIdx.x;
    const int lane = threadIdx.x;

    if (blk == 0) {
        if (lane < 18) {
            int j = lane / 6, wi = lane % 6;
            float s = 0.f;
            for (int m = 0; m < 16; ++m) s += Wf[j*80 + 64 + m] * Wq[m*6 + wi];
            ws_f[WS_MQ_F + lane] = s;
        } else if (lane < 21) {
            int j = lane - 18;
            float s = bf[j];
            for (int m = 0; m < 16; ++m) s += Wf[j*80 + 64 + m] * bq[m];
            ws_f[WS_CQ_F + j] = s;
        }
    } else if (blk <= 64) {
        // U_circ column j: amplitudes-in-lanes, one wave
        const int j = blk - 1;
        float re = (lane == j) ? 1.f : 0.f;
        float im = 0.f;
        for (int l = 0; l < n_layers; ++l) {
            for (int w = 0; w < NQ; ++w) {
                const float* g = qw + (l*NQ + w)*3;
                float phi = g[0], th = g[1], om = g[2];
                float c, s;  __sincosf(0.5f*th, &s, &c);
                float sa, ca; __sincosf(0.5f*(phi+om), &sa, &ca);
                float sb, cb; __sincosf(0.5f*(phi-om), &sb, &cb);
                float u00r =  c*ca, u00i = -c*sa;
                float u01r = -s*cb, u01i = -s*sb;
                float u10r =  s*cb, u10i = -s*sb;
                float u11r =  c*ca, u11i =  c*sa;
                int p = 5 - w, mask = 1 << p;
                float pre = __shfl_xor(re, mask, 64);
                float pim = __shfl_xor(im, mask, 64);
                int b = (lane >> p) & 1;
                float mr = b ? u11r : u00r, mi = b ? u11i : u00i;
                float pr = b ? u10r : u01r, pi = b ? u10i : u01i;
                float nre = mr*re - mi*im + pr*pre - pi*pim;
                float nim = mr*im + mi*re + pr*pim + pi*pre;
                re = nre; im = nim;
            }
            int r = l % (NQ-1) + 1;
            for (int w = 0; w < NQ; ++w) {
                int tgt = (w + r) % NQ;
                int tmask = 1 << (5 - tgt);
                float pre = __shfl_xor(re, tmask, 64);
                float pim = __shfl_xor(im, tmask, 64);
                int cs = (lane >> (5 - w)) & 1;
                re = cs ? pre : re;
                im = cs ? pim : im;
            }
        }
        ws_f[(lane*64 + j)*2 + 0] = re;   // U[i=lane][j].re
        ws_f[(lane*64 + j)*2 + 1] = im;
    } else {
        // W1 fp32 -> bf16 (row-major [n][k]), blocks 65..320
        int idx = (blk - 65)*512 + lane*8;
        if (idx < 64*2048) {
            float4 a0 = *(const float4*)(W1 + idx);
            float4 a1 = *(const float4*)(W1 + idx + 4);
            union { short8 v; __hip_bfloat162 h[4]; } u;
            float2 f;
            f.x=a0.x; f.y=a0.y; u.h[0] = __float22bfloat162_rn(f);
            f.x=a0.z; f.y=a0.w; u.h[1] = __float22bfloat162_rn(f);
            f.x=a1.x; f.y=a1.y; u.h[2] = __float22bfloat162_rn(f);
            f.x=a1.z; f.y=a1.w; u.h[3] = __float22bfloat162_rn(f);
            *(short8*)(w1bf + idx) = u.v;
        }
    }
}

__device__ __forceinline__ short8 cvt_bf16x8(float4 a0, float4 a1) {
    union { short8 v; __hip_bfloat162 h[4]; } u;
    float2 f;
    f.x=a0.x; f.y=a0.y; u.h[0] = __float22bfloat162_rn(f);
    f.x=a0.z; f.y=a0.w; u.h[1] = __float22bfloat162_rn(f);
    f.x=a1.x; f.y=a1.y; u.h[2] = __float22bfloat162_rn(f);
    f.x=a1.z; f.y=a1.w; u.h[3] = __float22bfloat162_rn(f);
    return u.v;
}

// ============ K1: fused quantum + GEMM + ReLU + 3-wide head ============
// grid B/32 = 512 blocks x 512 threads (8 waves, 32 rows/block).
// Smaller block -> 2-4 blocks/CU so barrier vmcnt-drains of one block are
// hidden by another block's compute (TLP over the per-chunk drain).
// Same swizzled double-buffered LDS A-pipeline (2 chunks in flight).
__global__ __launch_bounds__(512, 4) void fused_kernel(
    const float* __restrict__ xq, const float2* __restrict__ U,
    const float* __restrict__ ws_f,
    const float* __restrict__ xc, const short* __restrict__ w1bf,
    const float* __restrict__ b1, const float* __restrict__ Wf,
    float* __restrict__ out)
{
    const int tid  = threadIdx.x;
    const int lane = tid & 63;
    const int t    = __builtin_amdgcn_readfirstlane((int)(tid >> 6)); // wave 0..7
    const int blk  = blockIdx.x;

    __shared__ __align__(16) short Abuf[2][32*128];  // bf16, swizzled slots (16 KB)
    __shared__ float zbuf[16][32][6];                // 12 KB
    __shared__ float qres[32][3];
    __shared__ float cl[32][65];                     // 8.3 KB

    // ---- addressing ----
    const int wr = t >> 2, wc = t & 3;               // wr 0..1, wc 0..3
    // stage (writer) side: thread -> (row, 8-float group)
    const int srow = tid >> 4;          // 0..31
    const int sgrp = tid & 15;          // 0..15
    const float* asrc = xc + (size_t)(blk*32 + srow)*2048 + sgrp*8;
    const int adoff = srow*128 + ((sgrp ^ (srow & 7)) << 3);   // shorts
    // fragment (reader) side
    const int arow = wr*16 + (lane & 15);            // 0..31
    const int abase = arow*128;
    const int arx = arow & 7;
    const int a_l = lane >> 4;          // 0..3
    // B side
    const short* bp = w1bf + (wc*16 + (lane & 15))*2048 + a_l*8;

    // ---- load xq FIRST so Phase Q's waitcnt doesn't drain the pipeline ----
    const float* xrow = xq + (size_t)(blk*32 + (lane & 31))*6;
    float2 xq01 = *(const float2*)(xrow);
    float2 xq23 = *(const float2*)(xrow + 2);
    float2 xq45 = *(const float2*)(xrow + 4);

    // ---- prologue issues: A chunks 0,1 and B chunk 0 ----
    float4 sA0[2], sA1[2];
    sA0[0] = *(const float4*)(asrc + 0*128);
    sA1[0] = *(const float4*)(asrc + 0*128 + 4);
    sA0[1] = *(const float4*)(asrc + 1*128);
    sA1[1] = *(const float4*)(asrc + 1*128 + 4);
    short8 bv0 = *(const short8*)(bp + 0);
    short8 bv1 = *(const short8*)(bp + 32);
    short8 bv2 = *(const short8*)(bp + 64);
    short8 bv3 = *(const short8*)(bp + 96);

    // ---------- Phase Q: 16 virtual waves (vt = t*2 + lanehalf) of 32 lanes ----------
    {
        const int vt = (t << 1) | (lane >> 5);       // 0..15
        const float xs[6] = {xq01.x, xq01.y, xq23.x, xq23.y, xq45.x, xq45.y};
        float ah[8], al[8];
        ah[0] = 1.f;
        #pragma unroll
        for (int q = 0; q < 3; ++q) {
            float c, s; __sincosf(0.5f*xs[q], &s, &c);
            const int sz = 1 << q;
            #pragma unroll
            for (int m = sz-1; m >= 0; --m) {
                float v = ah[m];
                ah[2*m+1] = v*s;
                ah[2*m+0] = v*c;
            }
        }
        al[0] = 1.f;
        #pragma unroll
        for (int q = 0; q < 3; ++q) {
            float c, s; __sincosf(0.5f*xs[3+q], &s, &c);
            const int sz = 1 << q;
            #pragma unroll
            for (int m = sz-1; m >= 0; --m) {
                float v = al[m];
                al[2*m+1] = v*s;
                al[2*m+0] = v*c;
            }
        }

        float zp[6] = {0,0,0,0,0,0};
        const float2* Urow = U + vt*4*64;   // uniform within 32-lane half
        for (int ii = 0; ii < 4; ++ii) {
            float rr = 0.f, ri = 0.f;
            #pragma unroll
            for (int jh = 0; jh < 8; ++jh) {
                float sr = 0.f, si = 0.f;
                #pragma unroll
                for (int jl = 0; jl < 8; ++jl) {
                    float2 u = Urow[ii*64 + jh*8 + jl];
                    sr += u.x * al[jl];
                    si += u.y * al[jl];
                }
                rr += ah[jh] * sr;
                ri += ah[jh] * si;
            }
            float p = rr*rr + ri*ri;
            int i = vt*4 + ii;
            #pragma unroll
            for (int w = 0; w < 6; ++w) zp[w] += ((i >> (5-w)) & 1) ? -p : p;
        }
        #pragma unroll
        for (int w = 0; w < 6; ++w) zbuf[vt][lane & 31][w] = zp[w];
    }
    __syncthreads();
    if (t == 0 && lane < 32) {
        float z[6];
        #pragma unroll
        for (int w = 0; w < 6; ++w) {
            float s = 0.f;
            #pragma unroll
            for (int sbi = 0; sbi < 16; ++sbi) s += zbuf[sbi][lane][w];
            z[w] = s;
        }
        #pragma unroll
        for (int j = 0; j < 3; ++j) {
            float v = ws_f[WS_CQ_F + j];
            #pragma unroll
            for (int w = 0; w < 6; ++w) v += ws_f[WS_MQ_F + j*6 + w] * z[w];
            qres[lane][j] = v;
        }
    }

    // ---------- Phase G ----------
    // write chunk 0 into buf 0
    *(short8*)(&Abuf[0][adoff]) = cvt_bf16x8(sA0[0], sA1[0]);
    __syncthreads();   // buf0 ready (also orders qres for epilogue reads)

    floatx4 acc = {0,0,0,0};

    #pragma unroll
    for (int c = 0; c < 16; ++c) {
        const int cb = c & 1;

        // issue A loads for chunk c+2 (set cb was flushed to LDS already)
        if (c + 2 < 16) {
            sA0[cb] = *(const float4*)(asrc + (c+2)*128);
            sA1[cb] = *(const float4*)(asrc + (c+2)*128 + 4);
        }
        // issue B loads for chunk c+1
        short8 nb0, nb1, nb2, nb3;
        if (c + 1 < 16) {
            nb0 = *(const short8*)(bp + (c+1)*128 + 0);
            nb1 = *(const short8*)(bp + (c+1)*128 + 32);
            nb2 = *(const short8*)(bp + (c+1)*128 + 64);
            nb3 = *(const short8*)(bp + (c+1)*128 + 96);
        }

        // compute: 4 k-steps from Abuf[cb]
        const short* abp = &Abuf[cb][abase];
        short8 av0 = *(const short8*)(abp + ((((0*4 + a_l)) ^ arx) << 3));
        short8 av1 = *(const short8*)(abp + ((((1*4 + a_l)) ^ arx) << 3));
        short8 av2 = *(const short8*)(abp + ((((2*4 + a_l)) ^ arx) << 3));
        short8 av3 = *(const short8*)(abp + ((((3*4 + a_l)) ^ arx) << 3));
        acc = __builtin_amdgcn_mfma_f32_16x16x32_bf16(av0, bv0, acc, 0, 0, 0);
        acc = __builtin_amdgcn_mfma_f32_16x16x32_bf16(av1, bv1, acc, 0, 0, 0);
        acc = __builtin_amdgcn_mfma_f32_16x16x32_bf16(av2, bv2, acc, 0, 0, 0);
        acc = __builtin_amdgcn_mfma_f32_16x16x32_bf16(av3, bv3, acc, 0, 0, 0);

        // flush chunk c+1 (issued at c-1, landed by now) into buf cb^1
        if (c + 1 < 16) {
            *(short8*)(&Abuf[cb ^ 1][adoff]) = cvt_bf16x8(sA0[cb ^ 1], sA1[cb ^ 1]);
            bv0 = nb0; bv1 = nb1; bv2 = nb2; bv3 = nb3;
            __syncthreads();   // buf cb^1 ready for chunk c+1
        }
    }

    // epilogue: C layout col = wc*16 + (lane&15), row = wr*16 + (lane>>4)*4 + r
    const int rbase = wr*16 + (a_l * 4);
    const int c0 = wc*16 + (lane & 15);
    const float bb = b1[c0];
    #pragma unroll
    for (int r = 0; r < 4; ++r)
        cl[rbase + r][c0] = fmaxf(acc[r] + bb, 0.f);
    __syncthreads();

    // final head: wave j (0..2), lanes 0..31 handle output column j for 32 rows
    const int rr2 = lane & 31;
    if (t < 3 && lane < 32) {
        float v = 0.f;
        #pragma unroll
        for (int col = 0; col < 64; ++col) v += Wf[t*80 + col] * cl[rr2][col];
        int g = blk*32 + rr2;
        out[(size_t)g*3 + t] = v + qres[rr2][t];
    }
}

extern "C" void kernel_launch(void* const* d_in, const int* in_sizes, int n_in,
                              void* d_out, int out_size, void* d_ws, size_t ws_size,
                              hipStream_t stream) {
    const float* xc = (const float*)d_in[0];
    const float* xq = (const float*)d_in[1];
    const float* W1 = (const float*)d_in[2];
    const float* b1 = (const float*)d_in[3];
    const float* qw = (const float*)d_in[4];
    const float* Wq = (const float*)d_in[5];
    const float* bq = (const float*)d_in[6];
    const float* Wf = (const float*)d_in[7];
    const float* bf = (const float*)d_in[8];
    float* out = (float*)d_out;

    const int B = in_sizes[1] / NQ;                 // 16384
    const int n_layers = in_sizes[4] / (NQ * 3);    // 3

    char* ws = (char*)d_ws;
    float*  ws_f  = (float*)ws;
    float2* U     = (float2*)ws;
    short*  w1bf  = (short*)(ws + WS_W1BF_B);

    prep_kernel<<<dim3(321), dim3(64), 0, stream>>>(qw, n_layers, W1, Wq, bq, Wf, bf, ws_f, w1bf);
    fused_kernel<<<dim3(B/32), dim3(512), 0, stream>>>(xq, U, ws_f, xc, w1bf, b1, Wf, out);
}

// Round 6
// 220.887 us; speedup vs baseline: 1.0894x; 1.0894x over previous
//
#include <hip/hip_runtime.h>
#include <hip/hip_bf16.h>

#define NQ 6

typedef __attribute__((ext_vector_type(8))) short short8;
typedef __attribute__((ext_vector_type(4))) float floatx4;

// ---------------- ws layout (bytes) ----------------
// U_circ : float2[64*64]        @ 0        (32768 B)
// Mq     : float[18]            @ 32768
// cq     : float[3]             @ 32840
// W1bf   : short[64*2048]       @ 36864    (262144 B)
#define WS_MQ_F   8192        // float offset of Mq
#define WS_CQ_F   (8192+18)
#define WS_W1BF_B 36864

typedef const __attribute__((address_space(1))) void gvoid_t;
typedef __attribute__((address_space(3))) void lvoid_t;

// ============ K0: prep — U_circ columns, Mq/cq, W1->bf16 ============
__global__ __launch_bounds__(64) void prep_kernel(
    const float* __restrict__ qw, int n_layers,
    const float* __restrict__ W1, const float* __restrict__ Wq,
    const float* __restrict__ bq, const float* __restrict__ Wf,
    const float* __restrict__ bf, float* __restrict__ ws_f,
    short* __restrict__ w1bf)
{
    const int blk  = blockIdx.x;
    const int lane = threadIdx.x;

    if (blk == 0) {
        if (lane < 18) {
            int j = lane / 6, wi = lane % 6;
            float s = 0.f;
            for (int m = 0; m < 16; ++m) s += Wf[j*80 + 64 + m] * Wq[m*6 + wi];
            ws_f[WS_MQ_F + lane] = s;
        } else if (lane < 21) {
            int j = lane - 18;
            float s = bf[j];
            for (int m = 0; m < 16; ++m) s += Wf[j*80 + 64 + m] * bq[m];
            ws_f[WS_CQ_F + j] = s;
        }
    } else if (blk <= 64) {
        // U_circ column j: amplitudes-in-lanes, one wave
        const int j = blk - 1;
        float re = (lane == j) ? 1.f : 0.f;
        float im = 0.f;
        for (int l = 0; l < n_layers; ++l) {
            for (int w = 0; w < NQ; ++w) {
                const float* g = qw + (l*NQ + w)*3;
                float phi = g[0], th = g[1], om = g[2];
                float c, s;  __sincosf(0.5f*th, &s, &c);
                float sa, ca; __sincosf(0.5f*(phi+om), &sa, &ca);
                float sb, cb; __sincosf(0.5f*(phi-om), &sb, &cb);
                float u00r =  c*ca, u00i = -c*sa;
                float u01r = -s*cb, u01i = -s*sb;
                float u10r =  s*cb, u10i = -s*sb;
                float u11r =  c*ca, u11i =  c*sa;
                int p = 5 - w, mask = 1 << p;
                float pre = __shfl_xor(re, mask, 64);
                float pim = __shfl_xor(im, mask, 64);
                int b = (lane >> p) & 1;
                float mr = b ? u11r : u00r, mi = b ? u11i : u00i;
                float pr = b ? u10r : u01r, pi = b ? u10i : u01i;
                float nre = mr*re - mi*im + pr*pre - pi*pim;
                float nim = mr*im + mi*re + pr*pim + pi*pre;
                re = nre; im = nim;
            }
            int r = l % (NQ-1) + 1;
            for (int w = 0; w < NQ; ++w) {
                int tgt = (w + r) % NQ;
                int tmask = 1 << (5 - tgt);
                float pre = __shfl_xor(re, tmask, 64);
                float pim = __shfl_xor(im, tmask, 64);
                int cs = (lane >> (5 - w)) & 1;
                re = cs ? pre : re;
                im = cs ? pim : im;
            }
        }
        ws_f[(lane*64 + j)*2 + 0] = re;   // U[i=lane][j].re
        ws_f[(lane*64 + j)*2 + 1] = im;
    } else {
        // W1 fp32 -> bf16 (row-major [n][k]), blocks 65..320
        int idx = (blk - 65)*512 + lane*8;
        if (idx < 64*2048) {
            float4 a0 = *(const float4*)(W1 + idx);
            float4 a1 = *(const float4*)(W1 + idx + 4);
            union { short8 v; __hip_bfloat162 h[4]; } u;
            float2 f;
            f.x=a0.x; f.y=a0.y; u.h[0] = __float22bfloat162_rn(f);
            f.x=a0.z; f.y=a0.w; u.h[1] = __float22bfloat162_rn(f);
            f.x=a1.x; f.y=a1.y; u.h[2] = __float22bfloat162_rn(f);
            f.x=a1.z; f.y=a1.w; u.h[3] = __float22bfloat162_rn(f);
            *(short8*)(w1bf + idx) = u.v;
        }
    }
}

__device__ __forceinline__ short8 cvt_bf16x8(float4 a0, float4 a1) {
    union { short8 v; __hip_bfloat162 h[4]; } u;
    float2 f;
    f.x=a0.x; f.y=a0.y; u.h[0] = __float22bfloat162_rn(f);
    f.x=a0.z; f.y=a0.w; u.h[1] = __float22bfloat162_rn(f);
    f.x=a1.x; f.y=a1.y; u.h[2] = __float22bfloat162_rn(f);
    f.x=a1.z; f.y=a1.w; u.h[3] = __float22bfloat162_rn(f);
    return u.v;
}

// ============ K1: fused quantum + GEMM + ReLU + 3-wide head ============
// 512 blocks x 512 threads (8 waves, 32 rows). A: reg-staged 2 chunks
// ahead -> swizzled LDS dbuf. B: global_load_lds DMA 1 chunk ahead into
// swizzled LDS dbuf (zero register cost). zbuf/cl alias the Abuf region.
// ~48.5 KB LDS + ~55 VGPR -> 3 blocks/CU so barrier drains overlap.
__global__ __launch_bounds__(512, 6) void fused_kernel(
    const float* __restrict__ xq, const float2* __restrict__ U,
    const float* __restrict__ ws_f,
    const float* __restrict__ xc, const short* __restrict__ w1bf,
    const float* __restrict__ b1, const float* __restrict__ Wf,
    float* __restrict__ out)
{
    const int tid  = threadIdx.x;
    const int lane = tid & 63;
    const int t    = __builtin_amdgcn_readfirstlane((int)(tid >> 6)); // wave 0..7
    const int blk  = blockIdx.x;

    __shared__ __align__(16) char  smem0[16384];       // Abuf[2][4096sh] ∪ zbuf ∪ cl
    __shared__ __align__(16) short Bbuf[2][64*128];    // 32 KB, swizzled slots
    __shared__ float qres[32][3];

    short* Abuf = (short*)smem0;
    float (*zbuf)[32][6] = (float (*)[32][6])smem0;    // [8][32][6] = 6 KB
    float (*cl)[65]      = (float (*)[65])smem0;       // [32][65]   = 8.3 KB

    // ---- addressing ----
    const int wr = t >> 2, wc = t & 3;                 // wr 0..1, wc 0..3
    // A stage (writer): thread -> (row, 8-float group)
    const int srow = tid >> 4;                         // 0..31
    const int sgrp = tid & 15;                         // 0..15
    const float* asrc = xc + (size_t)(blk*32 + srow)*2048 + sgrp*8;
    const int adoff = srow*128 + ((sgrp ^ (srow & 7)) << 3);   // shorts
    // A fragment (reader)
    const int arow = wr*16 + (lane & 15);              // 0..31
    const int abase = arow*128;
    const int arx = arow & 7;
    const int a_l = lane >> 4;                         // 0..3
    // B fragment (reader)
    const int bcol = wc*16 + (lane & 15);              // 0..63
    const int bbase = bcol*128;
    const int brx = bcol & 7;
    // B DMA (writer): wave t, call q covers cols (t*2+q)*4 + (lane>>4),
    // lane's 16B lands at LDS (t*2+q)*1024 + lane*16 (linear); source is
    // pre-swizzled so LDS[col][slot] = B[col][kgrp = slot^(col&7)].
    const int dc0 = (t*2 + 0)*4 + (lane >> 4);
    const int dc1 = (t*2 + 1)*4 + (lane >> 4);
    const short* bsrc0 = w1bf + dc0*2048 + (((lane & 15) ^ (dc0 & 7)) << 3);
    const short* bsrc1 = w1bf + dc1*2048 + (((lane & 15) ^ (dc1 & 7)) << 3);

    // ---- early loads: xq (oldest -> Phase Q wait doesn't drain rest) ----
    const float* xrow = xq + (size_t)(blk*32 + (lane & 31))*6;
    float2 xq01 = *(const float2*)(xrow);
    float2 xq23 = *(const float2*)(xrow + 2);
    float2 xq45 = *(const float2*)(xrow + 4);

    // ---- prologue: B chunk 0 DMA + A chunk 0 reg load ----
    __builtin_amdgcn_global_load_lds((gvoid_t*)(bsrc0 + 0*128),
        (lvoid_t*)(&Bbuf[0][(t*2+0)*512]), 16, 0, 0);
    __builtin_amdgcn_global_load_lds((gvoid_t*)(bsrc1 + 0*128),
        (lvoid_t*)(&Bbuf[0][(t*2+1)*512]), 16, 0, 0);
    float4 sA0[2], sA1[2];
    sA0[0] = *(const float4*)(asrc + 0*128);
    sA1[0] = *(const float4*)(asrc + 0*128 + 4);

    // ---------- Phase Q: wave t handles U rows [t*8, t*8+8); lane&31 = batch ----------
    {
        const float xs[6] = {xq01.x, xq01.y, xq23.x, xq23.y, xq45.x, xq45.y};
        float ah[8], al[8];
        ah[0] = 1.f;
        #pragma unroll
        for (int q = 0; q < 3; ++q) {
            float c, s; __sincosf(0.5f*xs[q], &s, &c);
            const int sz = 1 << q;
            #pragma unroll
            for (int m = sz-1; m >= 0; --m) {
                float v = ah[m];
                ah[2*m+1] = v*s;
                ah[2*m+0] = v*c;
            }
        }
        al[0] = 1.f;
        #pragma unroll
        for (int q = 0; q < 3; ++q) {
            float c, s; __sincosf(0.5f*xs[3+q], &s, &c);
            const int sz = 1 << q;
            #pragma unroll
            for (int m = sz-1; m >= 0; --m) {
                float v = al[m];
                al[2*m+1] = v*s;
                al[2*m+0] = v*c;
            }
        }

        float zp[6] = {0,0,0,0,0,0};
        const float2* Urow = U + t*8*64;   // wave-uniform -> scalar loads
        for (int ii = 0; ii < 8; ++ii) {
            float rr = 0.f, ri = 0.f;
            #pragma unroll
            for (int jh = 0; jh < 8; ++jh) {
                float sr = 0.f, si = 0.f;
                #pragma unroll
                for (int jl = 0; jl < 8; ++jl) {
                    float2 u = Urow[ii*64 + jh*8 + jl];
                    sr += u.x * al[jl];
                    si += u.y * al[jl];
                }
                rr += ah[jh] * sr;
                ri += ah[jh] * si;
            }
            float p = rr*rr + ri*ri;
            int i = t*8 + ii;
            #pragma unroll
            for (int w = 0; w < 6; ++w) zp[w] += ((i >> (5-w)) & 1) ? -p : p;
        }
        if (lane < 32) {
            #pragma unroll
            for (int w = 0; w < 6; ++w) zbuf[t][lane][w] = zp[w];
        }
    }
    __syncthreads();                 // zbuf ready (also drains B0 DMA)
    if (t == 0 && lane < 32) {
        float z[6];
        #pragma unroll
        for (int w = 0; w < 6; ++w) {
            float s = 0.f;
            #pragma unroll
            for (int sbi = 0; sbi < 8; ++sbi) s += zbuf[sbi][lane][w];
            z[w] = s;
        }
        #pragma unroll
        for (int j = 0; j < 3; ++j) {
            float v = ws_f[WS_CQ_F + j];
            #pragma unroll
            for (int w = 0; w < 6; ++w) v += ws_f[WS_MQ_F + j*6 + w] * z[w];
            qres[lane][j] = v;
        }
    }
    // issue A chunk 1 while the reduce runs
    sA0[1] = *(const float4*)(asrc + 1*128);
    sA1[1] = *(const float4*)(asrc + 1*128 + 4);
    __syncthreads();                 // zbuf reads done -> Abuf region free

    // ---------- Phase G ----------
    *(short8*)(&Abuf[0*4096 + adoff]) = cvt_bf16x8(sA0[0], sA1[0]);
    __syncthreads();                 // Abuf[0] + Bbuf[0] ready

    floatx4 acc = {0,0,0,0};

    #pragma unroll
    for (int c = 0; c < 16; ++c) {
        const int cb = c & 1;

        // DMA B chunk c+1 into the non-active buffer (readers of that
        // parity finished at the end-of-(c-1) barrier)
        if (c + 1 < 16) {
            __builtin_amdgcn_global_load_lds((gvoid_t*)(bsrc0 + (c+1)*128),
                (lvoid_t*)(&Bbuf[cb ^ 1][(t*2+0)*512]), 16, 0, 0);
            __builtin_amdgcn_global_load_lds((gvoid_t*)(bsrc1 + (c+1)*128),
                (lvoid_t*)(&Bbuf[cb ^ 1][(t*2+1)*512]), 16, 0, 0);
        }
        // issue A loads for chunk c+2 (set cb was flushed at iter c-1)
        if (c + 2 < 16) {
            sA0[cb] = *(const float4*)(asrc + (c+2)*128);
            sA1[cb] = *(const float4*)(asrc + (c+2)*128 + 4);
        }

        // compute: 4 k-steps from LDS (both operands swizzled)
        const short* abp = &Abuf[cb*4096 + abase];
        const short* bbp = &Bbuf[cb][bbase];
        short8 av0 = *(const short8*)(abp + (((0*4 + a_l) ^ arx) << 3));
        short8 av1 = *(const short8*)(abp + (((1*4 + a_l) ^ arx) << 3));
        short8 av2 = *(const short8*)(abp + (((2*4 + a_l) ^ arx) << 3));
        short8 av3 = *(const short8*)(abp + (((3*4 + a_l) ^ arx) << 3));
        short8 bv0 = *(const short8*)(bbp + (((0*4 + a_l) ^ brx) << 3));
        short8 bv1 = *(const short8*)(bbp + (((1*4 + a_l) ^ brx) << 3));
        short8 bv2 = *(const short8*)(bbp + (((2*4 + a_l) ^ brx) << 3));
        short8 bv3 = *(const short8*)(bbp + (((3*4 + a_l) ^ brx) << 3));
        acc = __builtin_amdgcn_mfma_f32_16x16x32_bf16(av0, bv0, acc, 0, 0, 0);
        acc = __builtin_amdgcn_mfma_f32_16x16x32_bf16(av1, bv1, acc, 0, 0, 0);
        acc = __builtin_amdgcn_mfma_f32_16x16x32_bf16(av2, bv2, acc, 0, 0, 0);
        acc = __builtin_amdgcn_mfma_f32_16x16x32_bf16(av3, bv3, acc, 0, 0, 0);

        // flush A chunk c+1 (loaded at iter c-1) into the other buffer
        if (c + 1 < 16) {
            *(short8*)(&Abuf[(cb ^ 1)*4096 + adoff]) = cvt_bf16x8(sA0[cb ^ 1], sA1[cb ^ 1]);
            __syncthreads();         // next chunk's A+B ready
        }
    }
    __syncthreads();                 // all Abuf reads done before cl aliases it

    // epilogue: C layout col = wc*16 + (lane&15), row = wr*16 + a_l*4 + r
    const int rbase = wr*16 + a_l*4;
    const float bb = b1[bcol];
    #pragma unroll
    for (int r = 0; r < 4; ++r)
        cl[rbase + r][bcol] = fmaxf(acc[r] + bb, 0.f);
    __syncthreads();

    // final head: wave j (0..2), lanes 0..31 handle output column j for 32 rows
    const int rr2 = lane & 31;
    if (t < 3 && lane < 32) {
        float v = 0.f;
        #pragma unroll
        for (int col = 0; col < 64; ++col) v += Wf[t*80 + col] * cl[rr2][col];
        int g = blk*32 + rr2;
        out[(size_t)g*3 + t] = v + qres[rr2][t];
    }
}

extern "C" void kernel_launch(void* const* d_in, const int* in_sizes, int n_in,
                              void* d_out, int out_size, void* d_ws, size_t ws_size,
                              hipStream_t stream) {
    const float* xc = (const float*)d_in[0];
    const float* xq = (const float*)d_in[1];
    const float* W1 = (const float*)d_in[2];
    const float* b1 = (const float*)d_in[3];
    const float* qw = (const float*)d_in[4];
    const float* Wq = (const float*)d_in[5];
    const float* bq = (const float*)d_in[6];
    const float* Wf = (const float*)d_in[7];
    const float* bf = (const float*)d_in[8];
    float* out = (float*)d_out;

    const int B = in_sizes[1] / NQ;                 // 16384
    const int n_layers = in_sizes[4] / (NQ * 3);    // 3

    char* ws = (char*)d_ws;
    float*  ws_f  = (float*)ws;
    float2* U     = (float2*)ws;
    short*  w1bf  = (short*)(ws + WS_W1BF_B);

    prep_kernel<<<dim3(321), dim3(64), 0, stream>>>(qw, n_layers, W1, Wq, bq, Wf, bf, ws_f, w1bf);
    fused_kernel<<<dim3(B/32), dim3(512), 0, stream>>>(xq, U, ws_f, xc, w1bf, b1, Wf, out);
}